// Round 1
// baseline (739.045 us; speedup 1.0000x reference)
//
#include <hip/hip_runtime.h>
#include <stdint.h>

#define D_FEAT 256
#define NGRAPH 64
#define NSPLIT 8
#define BM 64
#define BK 32
#define LDR 40   // LDS row stride in bf16 elems (80B: 16B-aligned, 2-way-max bank pattern)

using f32x4 = __attribute__((ext_vector_type(4))) float;
using s16x8 = __attribute__((ext_vector_type(8))) short;
using s16x4 = __attribute__((ext_vector_type(4))) short;
using i32x4 = __attribute__((ext_vector_type(4))) int;

__device__ __forceinline__ unsigned short f2bf(float f) {
  union { float f; unsigned u; } v; v.f = f;
  return (unsigned short)((v.u + 0x7FFFu + ((v.u >> 16) & 1u)) >> 16);  // RNE
}

// ---------- CSR build ----------
__global__ void hist_k(const int* __restrict__ dst, int* __restrict__ counts, int E) {
  int e = blockIdx.x * blockDim.x + threadIdx.x;
  if (e < E) atomicAdd(&counts[dst[e]], 1);
}

__global__ __launch_bounds__(1024) void scan_k(const int* __restrict__ counts,
                                               int* __restrict__ off, int* __restrict__ cur,
                                               float* __restrict__ isd, int N) {
  __shared__ int part[1024];
  int t = threadIdx.x;
  int chunk = (N + 1023) >> 10;
  int lo = t * chunk;
  int hi = lo + chunk; if (hi > N) hi = N;
  int s = 0;
  for (int i = lo; i < hi; ++i) s += counts[i];
  part[t] = s;
  __syncthreads();
  for (int d = 1; d < 1024; d <<= 1) {
    int v = (t >= d) ? part[t - d] : 0;
    __syncthreads();
    part[t] += v;
    __syncthreads();
  }
  int base = part[t] - s;  // exclusive prefix
  for (int i = lo; i < hi; ++i) {
    off[i] = base; cur[i] = base;
    isd[i] = rsqrtf((float)(counts[i] + 1));  // +1 self-loop; deg>=1 always
    base += counts[i];
  }
  if (t == 1023) off[N] = part[1023];
}

__global__ void fill_k(const int* __restrict__ src, const int* __restrict__ dst,
                       int* __restrict__ cur, int* __restrict__ csr, int E) {
  int e = blockIdx.x * blockDim.x + threadIdx.x;
  if (e < E) {
    int d = dst[e];
    int pos = atomicAdd(&cur[d], 1);
    csr[pos] = src[e];
  }
}

// ---------- weight convert: W[k][n] f32 -> Wt[n][k] bf16 ----------
__global__ void wconv_k(const float* __restrict__ W0, const float* __restrict__ W1,
                        const float* __restrict__ W2, unsigned short* __restrict__ Wt) {
  int idx = blockIdx.x * blockDim.x + threadIdx.x;  // 0 .. 3*65536
  int w = idx >> 16; int r = idx & 65535;
  int k = r >> 8, n = r & 255;
  const float* W = (w == 0) ? W0 : (w == 1) ? W1 : W2;
  Wt[(size_t)w * 65536 + n * 256 + k] = f2bf(W[k * 256 + n]);
}

// ---------- GEMM: P[i][:] = (X[i][:] @ W) * isd[i], bf16 MFMA ----------
__global__ __launch_bounds__(256) void gemm_k(const float* __restrict__ X,
                                              const unsigned short* __restrict__ Wt,
                                              float* __restrict__ P,
                                              const float* __restrict__ isd, int M) {
  __shared__ __align__(16) short As[BM * LDR];       // 5120 B
  __shared__ __align__(16) short Bs[D_FEAT * LDR];   // 20480 B
  int t = threadIdx.x;
  int lane = t & 63;
  int wave = t >> 6;              // 0..3 -> 64-col quadrant
  int row0 = blockIdx.x * BM;
  int l15 = lane & 15;
  int l4  = lane >> 4;

  f32x4 acc[4][4];
  for (int m = 0; m < 4; ++m)
    for (int n = 0; n < 4; ++n)
      acc[m][n] = (f32x4){0.f, 0.f, 0.f, 0.f};

  for (int k0 = 0; k0 < D_FEAT; k0 += BK) {
    // stage A: 64 rows x 32 k, f32 -> bf16
    for (int i = 0; i < 2; ++i) {
      int g = t + i * 256;            // 0..511
      int r = g >> 3, c4 = g & 7;
      int grow = row0 + r;
      f32x4 v = (f32x4){0.f, 0.f, 0.f, 0.f};
      if (grow < M) v = *(const f32x4*)(X + (size_t)grow * D_FEAT + k0 + c4 * 4);
      s16x4 b;
      b.x = (short)f2bf(v.x); b.y = (short)f2bf(v.y);
      b.z = (short)f2bf(v.z); b.w = (short)f2bf(v.w);
      *(s16x4*)&As[r * LDR + c4 * 4] = b;
    }
    // stage B: Wt rows (already [n][k] bf16), 256 rows x 32 k
    for (int i = 0; i < 4; ++i) {
      int g = t + i * 256;            // 0..1023
      int n = g >> 2, c = g & 3;
      i32x4 v = *(const i32x4*)(Wt + (size_t)n * D_FEAT + k0 + c * 8);
      *(i32x4*)&Bs[n * LDR + c * 8] = v;
    }
    __syncthreads();
    s16x8 a[4], b[4];
    for (int m = 0; m < 4; ++m)
      a[m] = *(const s16x8*)&As[(m * 16 + l15) * LDR + l4 * 8];
    for (int n = 0; n < 4; ++n)
      b[n] = *(const s16x8*)&Bs[(wave * 64 + n * 16 + l15) * LDR + l4 * 8];
    for (int m = 0; m < 4; ++m)
      for (int n = 0; n < 4; ++n)
        acc[m][n] = __builtin_amdgcn_mfma_f32_16x16x32_bf16(a[m], b[n], acc[m][n], 0, 0, 0);
    __syncthreads();
  }

  // epilogue: C/D layout col=lane&15, row=4*(lane>>4)+reg
  for (int m = 0; m < 4; ++m) {
    int rbase = row0 + m * 16 + l4 * 4;
    for (int r = 0; r < 4; ++r) {
      int row = rbase + r;
      if (row >= M) continue;
      float sc = isd[row];
      for (int n = 0; n < 4; ++n) {
        int col = wave * 64 + n * 16 + l15;
        P[(size_t)row * D_FEAT + col] = acc[m][n][r] * sc;
      }
    }
  }
}

// ---------- aggregation: H[i] = relu((P[i] + sum_{s in N(i)} P[s]) * isd[i] + b) ----------
__global__ __launch_bounds__(256) void agg_k(const float* __restrict__ P,
                                             const int* __restrict__ csr,
                                             const int* __restrict__ off,
                                             const float* __restrict__ isd,
                                             const float* __restrict__ bias,
                                             float* __restrict__ H, int N) {
  int gid = blockIdx.x * blockDim.x + threadIdx.x;
  int node = gid >> 6;
  int lane = gid & 63;
  if (node >= N) return;
  const f32x4* P4 = (const f32x4*)P;
  f32x4 acc = P4[(size_t)node * 64 + lane];   // self-loop term (P already *isd[src])
  int lo = off[node], hi = off[node + 1];
  for (int e = lo; e < hi; ++e) {
    int s = csr[e];
    acc += P4[(size_t)s * 64 + lane];
  }
  float sc = isd[node];
  f32x4 bb = *(const f32x4*)(bias + lane * 4);
  f32x4 o;
  o.x = fmaxf(acc.x * sc + bb.x, 0.f);
  o.y = fmaxf(acc.y * sc + bb.y, 0.f);
  o.z = fmaxf(acc.z * sc + bb.z, 0.f);
  o.w = fmaxf(acc.w * sc + bb.w, 0.f);
  ((f32x4*)H)[(size_t)node * 64 + lane] = o;
}

// ---------- pooling ----------
__device__ __forceinline__ int lower_bound_batch(const int* __restrict__ b, int N, int v) {
  int lo = 0, hi = N;
  while (lo < hi) { int mid = (lo + hi) >> 1; if (b[mid] < v) lo = mid + 1; else hi = mid; }
  return lo;
}

__global__ __launch_bounds__(256) void pool_k(const float* __restrict__ H,
                                              const int* __restrict__ batch,
                                              float* __restrict__ pp, int N) {
  int g = blockIdx.x >> 3;
  int s = blockIdx.x & (NSPLIT - 1);
  int c = threadIdx.x;
  int lo = lower_bound_batch(batch, N, g);
  int hi = lower_bound_batch(batch, N, g + 1);
  int len = hi - lo;
  int slo = lo + (int)(((long long)len * s) >> 3);
  int shi = lo + (int)(((long long)len * (s + 1)) >> 3);
  float sum = 0.f;
  for (int i = slo; i < shi; ++i) sum += H[(size_t)i * D_FEAT + c];
  pp[(g * NSPLIT + s) * D_FEAT + c] = sum;
}

// ---------- FC head ----------
__global__ __launch_bounds__(256) void fc_k(const float* __restrict__ pp,
                                            const int* __restrict__ batch,
                                            const float* __restrict__ fc1w, const float* __restrict__ fc1b,
                                            const float* __restrict__ fc2w, const float* __restrict__ fc2b,
                                            float* __restrict__ out, int N) {
  __shared__ float pl[D_FEAT];
  __shared__ float h1[D_FEAT];
  int g = blockIdx.x, j = threadIdx.x;
  int lo = lower_bound_batch(batch, N, g);
  int hi = lower_bound_batch(batch, N, g + 1);
  float cnt = fmaxf((float)(hi - lo), 1.f);
  float sum = 0.f;
  for (int s = 0; s < NSPLIT; ++s) sum += pp[(g * NSPLIT + s) * D_FEAT + j];
  pl[j] = sum / cnt;
  __syncthreads();
  float a = fc1b[j];
  for (int k = 0; k < D_FEAT; ++k) a += pl[k] * fc1w[k * D_FEAT + j];
  h1[j] = fmaxf(a, 0.f);
  __syncthreads();
  if (j < 128) {
    float o = fc2b[j];
    for (int k = 0; k < D_FEAT; ++k) o += h1[k] * fc2w[k * 128 + j];
    out[g * 128 + j] = o;
  }
}

extern "C" void kernel_launch(void* const* d_in, const int* in_sizes, int n_in,
                              void* d_out, int out_size, void* d_ws, size_t ws_size,
                              hipStream_t stream) {
  const float* x    = (const float*)d_in[0];
  const int*   ei   = (const int*)d_in[1];
  const int*   batch= (const int*)d_in[2];
  const float* W0   = (const float*)d_in[3];
  const float* b0   = (const float*)d_in[4];
  const float* W1   = (const float*)d_in[5];
  const float* b1   = (const float*)d_in[6];
  const float* W2   = (const float*)d_in[7];
  const float* b2   = (const float*)d_in[8];
  const float* fc1w = (const float*)d_in[9];
  const float* fc1b = (const float*)d_in[10];
  const float* fc2w = (const float*)d_in[11];
  const float* fc2b = (const float*)d_in[12];
  float* out = (float*)d_out;

  int N = in_sizes[0] / D_FEAT;   // 50000
  int E = in_sizes[1] / 2;        // 800000
  const int* srcE = ei;
  const int* dstE = ei + E;

  // workspace carve (~108 MB)
  char* w = (char*)d_ws;
  auto alloc = [&](size_t bytes) { char* p = w; w += (bytes + 255) & ~(size_t)255; return p; };
  int*   counts = (int*)  alloc((size_t)N * 4);
  int*   off    = (int*)  alloc((size_t)(N + 1) * 4);
  int*   cur    = (int*)  alloc((size_t)N * 4);
  float* isd    = (float*)alloc((size_t)N * 4);
  int*   csr    = (int*)  alloc((size_t)E * 4);
  unsigned short* Wt = (unsigned short*)alloc((size_t)3 * 65536 * 2);
  float* P      = (float*)alloc((size_t)N * D_FEAT * 4);
  float* H      = (float*)alloc((size_t)N * D_FEAT * 4);
  float* pp     = (float*)alloc((size_t)NGRAPH * NSPLIT * D_FEAT * 4);

  hipMemsetAsync(counts, 0, (size_t)N * 4, stream);
  hist_k<<<(E + 255) / 256, 256, 0, stream>>>(dstE, counts, E);
  scan_k<<<1, 1024, 0, stream>>>(counts, off, cur, isd, N);
  fill_k<<<(E + 255) / 256, 256, 0, stream>>>(srcE, dstE, cur, csr, E);
  wconv_k<<<768, 256, 0, stream>>>(W0, W1, W2, Wt);

  int gblocks = (N + BM - 1) / BM;
  int ablocks = (N * 64 + 255) / 256;

  gemm_k<<<gblocks, 256, 0, stream>>>(x, Wt,             P, isd, N);
  agg_k <<<ablocks, 256, 0, stream>>>(P, csr, off, isd, b0, H, N);
  gemm_k<<<gblocks, 256, 0, stream>>>(H, Wt + 65536,     P, isd, N);
  agg_k <<<ablocks, 256, 0, stream>>>(P, csr, off, isd, b1, H, N);
  gemm_k<<<gblocks, 256, 0, stream>>>(H, Wt + 2 * 65536, P, isd, N);
  agg_k <<<ablocks, 256, 0, stream>>>(P, csr, off, isd, b2, H, N);

  pool_k<<<NGRAPH * NSPLIT, 256, 0, stream>>>(H, batch, pp, N);
  fc_k  <<<NGRAPH, 256, 0, stream>>>(pp, batch, fc1w, fc1b, fc2w, fc2b, out, N);
}

// Round 2
// 614.540 us; speedup vs baseline: 1.2026x; 1.2026x over previous
//
#include <hip/hip_runtime.h>
#include <stdint.h>

#define D_FEAT 256
#define NGRAPH 64
#define NSPLIT 8
#define BM 64
#define BK 32
#define LDR 40   // LDS row stride in bf16 elems (80B: 16B-aligned, 2-way-max bank pattern)
#define SCAN_CHUNK 1024

using f32x4 = __attribute__((ext_vector_type(4))) float;
using s16x8 = __attribute__((ext_vector_type(8))) short;
using s16x4 = __attribute__((ext_vector_type(4))) short;
using i32x4 = __attribute__((ext_vector_type(4))) int;

__device__ __forceinline__ unsigned short f2bf(float f) {
  union { float f; unsigned u; } v; v.f = f;
  return (unsigned short)((v.u + 0x7FFFu + ((v.u >> 16) & 1u)) >> 16);  // RNE
}

// ---------- CSR build ----------
__global__ void hist_k(const int* __restrict__ dst, int* __restrict__ counts, int E) {
  int e = blockIdx.x * blockDim.x + threadIdx.x;
  if (e < E) atomicAdd(&counts[dst[e]], 1);
}

// Phase A: per-block (1024-elem chunk) sums
__global__ __launch_bounds__(256) void bsum_k(const int* __restrict__ counts,
                                              int* __restrict__ bsum, int N) {
  int base = blockIdx.x * SCAN_CHUNK;
  int t = threadIdx.x;
  int idx = base + t * 4;
  int s = 0;
  if (idx + 3 < N) {
    i32x4 v = *(const i32x4*)(counts + idx);
    s = v.x + v.y + v.z + v.w;
  } else {
    for (int j = 0; j < 4; ++j) if (idx + j < N) s += counts[idx + j];
  }
  for (int d = 1; d < 64; d <<= 1) s += __shfl_xor(s, d);
  __shared__ int ws[4];
  if ((t & 63) == 0) ws[t >> 6] = s;
  __syncthreads();
  if (t == 0) bsum[blockIdx.x] = ws[0] + ws[1] + ws[2] + ws[3];
}

// Phase B: scan the block sums (nb <= 1024), write total to offN
__global__ __launch_bounds__(1024) void bscan_k(const int* __restrict__ bsum,
                                                int* __restrict__ boff,
                                                int* __restrict__ offN, int nb) {
  __shared__ int part[1024];
  int t = threadIdx.x;
  int v = (t < nb) ? bsum[t] : 0;
  part[t] = v;
  __syncthreads();
  for (int d = 1; d < 1024; d <<= 1) {
    int u = (t >= d) ? part[t - d] : 0;
    __syncthreads();
    part[t] += u;
    __syncthreads();
  }
  if (t < nb) boff[t] = part[t] - v;
  if (t == 1023) offN[0] = part[1023];
}

// Phase C: in-block scan + block offset -> off/cur/isd
__global__ __launch_bounds__(256) void fillscan_k(const int* __restrict__ counts,
                                                  const int* __restrict__ boff,
                                                  int* __restrict__ off, int* __restrict__ cur,
                                                  float* __restrict__ isd, int N) {
  int b = blockIdx.x;
  int base = b * SCAN_CHUNK;
  int t = threadIdx.x;
  int idx = base + t * 4;
  int c[4];
  int s = 0;
  for (int j = 0; j < 4; ++j) {
    c[j] = (idx + j < N) ? counts[idx + j] : 0;
    s += c[j];
  }
  int inc = s;
  int lane = t & 63;
  for (int d = 1; d < 64; d <<= 1) {
    int u = __shfl_up(inc, d);
    if (lane >= d) inc += u;
  }
  __shared__ int wtot[4];
  if (lane == 63) wtot[t >> 6] = inc;
  __syncthreads();
  int woff = 0;
  for (int w = 0; w < (t >> 6); ++w) woff += wtot[w];
  int ex = boff[b] + woff + inc - s;  // exclusive prefix for this thread's 4 elems
  for (int j = 0; j < 4; ++j) {
    int i = idx + j;
    if (i < N) {
      off[i] = ex;
      cur[i] = ex;
      isd[i] = rsqrtf((float)(c[j] + 1));  // +1 self-loop
      ex += c[j];
    }
  }
}

__global__ void fill_k(const int* __restrict__ src, const int* __restrict__ dst,
                       int* __restrict__ cur, int* __restrict__ csr, int E) {
  int e = blockIdx.x * blockDim.x + threadIdx.x;
  if (e < E) {
    int d = dst[e];
    int pos = atomicAdd(&cur[d], 1);
    csr[pos] = src[e];
  }
}

// ---------- weight convert: W[k][n] f32 -> Wt[n][k] bf16 ----------
__global__ void wconv_k(const float* __restrict__ W0, const float* __restrict__ W1,
                        const float* __restrict__ W2, unsigned short* __restrict__ Wt) {
  int idx = blockIdx.x * blockDim.x + threadIdx.x;  // 0 .. 3*65536
  int w = idx >> 16; int r = idx & 65535;
  int k = r >> 8, n = r & 255;
  const float* W = (w == 0) ? W0 : (w == 1) ? W1 : W2;
  Wt[(size_t)w * 65536 + n * 256 + k] = f2bf(W[k * 256 + n]);
}

// ---------- GEMM: P[i][:] = (X[i][:] @ W) * isd[i], bf16 MFMA ----------
__global__ __launch_bounds__(256) void gemm_k(const float* __restrict__ X,
                                              const unsigned short* __restrict__ Wt,
                                              float* __restrict__ P,
                                              const float* __restrict__ isd, int M) {
  __shared__ __align__(16) short As[BM * LDR];       // 5120 B
  __shared__ __align__(16) short Bs[D_FEAT * LDR];   // 20480 B
  int t = threadIdx.x;
  int lane = t & 63;
  int wave = t >> 6;              // 0..3 -> 64-col quadrant
  int row0 = blockIdx.x * BM;
  int l15 = lane & 15;
  int l4  = lane >> 4;

  f32x4 acc[4][4];
  for (int m = 0; m < 4; ++m)
    for (int n = 0; n < 4; ++n)
      acc[m][n] = (f32x4){0.f, 0.f, 0.f, 0.f};

  for (int k0 = 0; k0 < D_FEAT; k0 += BK) {
    // stage A: 64 rows x 32 k, f32 -> bf16
    for (int i = 0; i < 2; ++i) {
      int g = t + i * 256;            // 0..511
      int r = g >> 3, c4 = g & 7;
      int grow = row0 + r;
      f32x4 v = (f32x4){0.f, 0.f, 0.f, 0.f};
      if (grow < M) v = *(const f32x4*)(X + (size_t)grow * D_FEAT + k0 + c4 * 4);
      s16x4 b;
      b.x = (short)f2bf(v.x); b.y = (short)f2bf(v.y);
      b.z = (short)f2bf(v.z); b.w = (short)f2bf(v.w);
      *(s16x4*)&As[r * LDR + c4 * 4] = b;
    }
    // stage B: Wt rows (already [n][k] bf16), 256 rows x 32 k
    for (int i = 0; i < 4; ++i) {
      int g = t + i * 256;            // 0..1023
      int n = g >> 2, c = g & 3;
      i32x4 v = *(const i32x4*)(Wt + (size_t)n * D_FEAT + k0 + c * 8);
      *(i32x4*)&Bs[n * LDR + c * 8] = v;
    }
    __syncthreads();
    s16x8 a[4], b[4];
    for (int m = 0; m < 4; ++m)
      a[m] = *(const s16x8*)&As[(m * 16 + l15) * LDR + l4 * 8];
    for (int n = 0; n < 4; ++n)
      b[n] = *(const s16x8*)&Bs[(wave * 64 + n * 16 + l15) * LDR + l4 * 8];
    for (int m = 0; m < 4; ++m)
      for (int n = 0; n < 4; ++n)
        acc[m][n] = __builtin_amdgcn_mfma_f32_16x16x32_bf16(a[m], b[n], acc[m][n], 0, 0, 0);
    __syncthreads();
  }

  // epilogue: C/D layout col=lane&15, row=4*(lane>>4)+reg
  for (int m = 0; m < 4; ++m) {
    int rbase = row0 + m * 16 + l4 * 4;
    for (int r = 0; r < 4; ++r) {
      int row = rbase + r;
      if (row >= M) continue;
      float sc = isd[row];
      for (int n = 0; n < 4; ++n) {
        int col = wave * 64 + n * 16 + l15;
        P[(size_t)row * D_FEAT + col] = acc[m][n][r] * sc;
      }
    }
  }
}

// ---------- aggregation: H[i] = relu((P[i] + sum_{s in N(i)} P[s]) * isd[i] + b) ----------
__global__ __launch_bounds__(256) void agg_k(const float* __restrict__ P,
                                             const int* __restrict__ csr,
                                             const int* __restrict__ off,
                                             const float* __restrict__ isd,
                                             const float* __restrict__ bias,
                                             float* __restrict__ H, int N) {
  int gid = blockIdx.x * blockDim.x + threadIdx.x;
  int node = gid >> 6;
  int lane = gid & 63;
  if (node >= N) return;
  const f32x4* P4 = (const f32x4*)P;
  f32x4 acc = P4[(size_t)node * 64 + lane];   // self-loop term (P already *isd[src])
  int lo = off[node], hi = off[node + 1];
  for (int e = lo; e < hi; ++e) {
    int s = csr[e];
    acc += P4[(size_t)s * 64 + lane];
  }
  float sc = isd[node];
  f32x4 bb = *(const f32x4*)(bias + lane * 4);
  f32x4 o;
  o.x = fmaxf(acc.x * sc + bb.x, 0.f);
  o.y = fmaxf(acc.y * sc + bb.y, 0.f);
  o.z = fmaxf(acc.z * sc + bb.z, 0.f);
  o.w = fmaxf(acc.w * sc + bb.w, 0.f);
  ((f32x4*)H)[(size_t)node * 64 + lane] = o;
}

// ---------- pooling ----------
__device__ __forceinline__ int lower_bound_batch(const int* __restrict__ b, int N, int v) {
  int lo = 0, hi = N;
  while (lo < hi) { int mid = (lo + hi) >> 1; if (b[mid] < v) lo = mid + 1; else hi = mid; }
  return lo;
}

__global__ __launch_bounds__(256) void pool_k(const float* __restrict__ H,
                                              const int* __restrict__ batch,
                                              float* __restrict__ pp, int N) {
  int g = blockIdx.x >> 3;
  int s = blockIdx.x & (NSPLIT - 1);
  int c = threadIdx.x;
  int lo = lower_bound_batch(batch, N, g);
  int hi = lower_bound_batch(batch, N, g + 1);
  int len = hi - lo;
  int slo = lo + (int)(((long long)len * s) >> 3);
  int shi = lo + (int)(((long long)len * (s + 1)) >> 3);
  float sum = 0.f;
  for (int i = slo; i < shi; ++i) sum += H[(size_t)i * D_FEAT + c];
  pp[(g * NSPLIT + s) * D_FEAT + c] = sum;
}

// ---------- FC head ----------
__global__ __launch_bounds__(256) void fc_k(const float* __restrict__ pp,
                                            const int* __restrict__ batch,
                                            const float* __restrict__ fc1w, const float* __restrict__ fc1b,
                                            const float* __restrict__ fc2w, const float* __restrict__ fc2b,
                                            float* __restrict__ out, int N) {
  __shared__ float pl[D_FEAT];
  __shared__ float h1[D_FEAT];
  int g = blockIdx.x, j = threadIdx.x;
  int lo = lower_bound_batch(batch, N, g);
  int hi = lower_bound_batch(batch, N, g + 1);
  float cnt = fmaxf((float)(hi - lo), 1.f);
  float sum = 0.f;
  for (int s = 0; s < NSPLIT; ++s) sum += pp[(g * NSPLIT + s) * D_FEAT + j];
  pl[j] = sum / cnt;
  __syncthreads();
  float a = fc1b[j];
  for (int k = 0; k < D_FEAT; ++k) a += pl[k] * fc1w[k * D_FEAT + j];
  h1[j] = fmaxf(a, 0.f);
  __syncthreads();
  if (j < 128) {
    float o = fc2b[j];
    for (int k = 0; k < D_FEAT; ++k) o += h1[k] * fc2w[k * 128 + j];
    out[g * 128 + j] = o;
  }
}

extern "C" void kernel_launch(void* const* d_in, const int* in_sizes, int n_in,
                              void* d_out, int out_size, void* d_ws, size_t ws_size,
                              hipStream_t stream) {
  const float* x    = (const float*)d_in[0];
  const int*   ei   = (const int*)d_in[1];
  const int*   batch= (const int*)d_in[2];
  const float* W0   = (const float*)d_in[3];
  const float* b0   = (const float*)d_in[4];
  const float* W1   = (const float*)d_in[5];
  const float* b1   = (const float*)d_in[6];
  const float* W2   = (const float*)d_in[7];
  const float* b2   = (const float*)d_in[8];
  const float* fc1w = (const float*)d_in[9];
  const float* fc1b = (const float*)d_in[10];
  const float* fc2w = (const float*)d_in[11];
  const float* fc2b = (const float*)d_in[12];
  float* out = (float*)d_out;

  int N = in_sizes[0] / D_FEAT;   // 50000
  int E = in_sizes[1] / 2;        // 800000
  const int* srcE = ei;
  const int* dstE = ei + E;
  int nb = (N + SCAN_CHUNK - 1) / SCAN_CHUNK;  // 49

  // workspace carve (~108 MB)
  char* w = (char*)d_ws;
  auto alloc = [&](size_t bytes) { char* p = w; w += (bytes + 255) & ~(size_t)255; return p; };
  int*   counts = (int*)  alloc((size_t)N * 4);
  int*   off    = (int*)  alloc((size_t)(N + 1) * 4);
  int*   cur    = (int*)  alloc((size_t)N * 4);
  float* isd    = (float*)alloc((size_t)N * 4);
  int*   csr    = (int*)  alloc((size_t)E * 4);
  int*   bsum   = (int*)  alloc((size_t)nb * 4);
  int*   boff   = (int*)  alloc((size_t)nb * 4);
  unsigned short* Wt = (unsigned short*)alloc((size_t)3 * 65536 * 2);
  float* P      = (float*)alloc((size_t)N * D_FEAT * 4);
  float* H      = (float*)alloc((size_t)N * D_FEAT * 4);
  float* pp     = (float*)alloc((size_t)NGRAPH * NSPLIT * D_FEAT * 4);

  hipMemsetAsync(counts, 0, (size_t)N * 4, stream);
  hist_k<<<(E + 255) / 256, 256, 0, stream>>>(dstE, counts, E);
  bsum_k<<<nb, 256, 0, stream>>>(counts, bsum, N);
  bscan_k<<<1, 1024, 0, stream>>>(bsum, boff, off + N, nb);
  fillscan_k<<<nb, 256, 0, stream>>>(counts, boff, off, cur, isd, N);
  fill_k<<<(E + 255) / 256, 256, 0, stream>>>(srcE, dstE, cur, csr, E);
  wconv_k<<<768, 256, 0, stream>>>(W0, W1, W2, Wt);

  int gblocks = (N + BM - 1) / BM;
  int ablocks = (N * 64 + 255) / 256;

  gemm_k<<<gblocks, 256, 0, stream>>>(x, Wt,             P, isd, N);
  agg_k <<<ablocks, 256, 0, stream>>>(P, csr, off, isd, b0, H, N);
  gemm_k<<<gblocks, 256, 0, stream>>>(H, Wt + 65536,     P, isd, N);
  agg_k <<<ablocks, 256, 0, stream>>>(P, csr, off, isd, b1, H, N);
  gemm_k<<<gblocks, 256, 0, stream>>>(H, Wt + 2 * 65536, P, isd, N);
  agg_k <<<ablocks, 256, 0, stream>>>(P, csr, off, isd, b2, H, N);

  pool_k<<<NGRAPH * NSPLIT, 256, 0, stream>>>(H, batch, pp, N);
  fc_k  <<<NGRAPH, 256, 0, stream>>>(pp, batch, fc1w, fc1b, fc2w, fc2b, out, N);
}

// Round 3
// 409.081 us; speedup vs baseline: 1.8066x; 1.5022x over previous
//
#include <hip/hip_runtime.h>
#include <stdint.h>

#define D_FEAT 256
#define NGRAPH 64
#define NSPLIT 8
#define BM 64
#define BK 32
#define LDR 40   // LDS row stride in bf16 elems (80B: 16B-aligned, 2-way-max bank pattern)
#define SCAN_CHUNK 1024

using f32x4 = __attribute__((ext_vector_type(4))) float;
using s16x8 = __attribute__((ext_vector_type(8))) short;
using s16x4 = __attribute__((ext_vector_type(4))) short;
using i32x4 = __attribute__((ext_vector_type(4))) int;

__device__ __forceinline__ unsigned short f2bf(float f) {
  union { float f; unsigned u; } v; v.f = f;
  return (unsigned short)((v.u + 0x7FFFu + ((v.u >> 16) & 1u)) >> 16);  // RNE
}
__device__ __forceinline__ float bf2f(unsigned short h) {
  union { unsigned u; float f; } v; v.u = ((unsigned)h) << 16; return v.f;
}
__device__ __forceinline__ f32x4 bf4_to_f32(s16x4 v) {
  f32x4 r;
  r.x = bf2f((unsigned short)v.x);
  r.y = bf2f((unsigned short)v.y);
  r.z = bf2f((unsigned short)v.z);
  r.w = bf2f((unsigned short)v.w);
  return r;
}

// ---------- CSR build ----------
__global__ void hist_k(const int* __restrict__ dst, int* __restrict__ counts, int E) {
  int e = blockIdx.x * blockDim.x + threadIdx.x;
  if (e < E) atomicAdd(&counts[dst[e]], 1);
}

// Phase A: per-block (1024-elem chunk) sums
__global__ __launch_bounds__(256) void bsum_k(const int* __restrict__ counts,
                                              int* __restrict__ bsum, int N) {
  int base = blockIdx.x * SCAN_CHUNK;
  int t = threadIdx.x;
  int idx = base + t * 4;
  int s = 0;
  if (idx + 3 < N) {
    i32x4 v = *(const i32x4*)(counts + idx);
    s = v.x + v.y + v.z + v.w;
  } else {
    for (int j = 0; j < 4; ++j) if (idx + j < N) s += counts[idx + j];
  }
  for (int d = 1; d < 64; d <<= 1) s += __shfl_xor(s, d);
  __shared__ int ws[4];
  if ((t & 63) == 0) ws[t >> 6] = s;
  __syncthreads();
  if (t == 0) bsum[blockIdx.x] = ws[0] + ws[1] + ws[2] + ws[3];
}

// Phase B: scan the block sums (nb <= 1024), write total to offN
__global__ __launch_bounds__(1024) void bscan_k(const int* __restrict__ bsum,
                                                int* __restrict__ boff,
                                                int* __restrict__ offN, int nb) {
  __shared__ int part[1024];
  int t = threadIdx.x;
  int v = (t < nb) ? bsum[t] : 0;
  part[t] = v;
  __syncthreads();
  for (int d = 1; d < 1024; d <<= 1) {
    int u = (t >= d) ? part[t - d] : 0;
    __syncthreads();
    part[t] += u;
    __syncthreads();
  }
  if (t < nb) boff[t] = part[t] - v;
  if (t == 1023) offN[0] = part[1023];
}

// Phase C: in-block scan + block offset -> off/cur/isd
__global__ __launch_bounds__(256) void fillscan_k(const int* __restrict__ counts,
                                                  const int* __restrict__ boff,
                                                  int* __restrict__ off, int* __restrict__ cur,
                                                  float* __restrict__ isd, int N) {
  int b = blockIdx.x;
  int base = b * SCAN_CHUNK;
  int t = threadIdx.x;
  int idx = base + t * 4;
  int c[4];
  int s = 0;
  for (int j = 0; j < 4; ++j) {
    c[j] = (idx + j < N) ? counts[idx + j] : 0;
    s += c[j];
  }
  int inc = s;
  int lane = t & 63;
  for (int d = 1; d < 64; d <<= 1) {
    int u = __shfl_up(inc, d);
    if (lane >= d) inc += u;
  }
  __shared__ int wtot[4];
  if (lane == 63) wtot[t >> 6] = inc;
  __syncthreads();
  int woff = 0;
  for (int w = 0; w < (t >> 6); ++w) woff += wtot[w];
  int ex = boff[b] + woff + inc - s;  // exclusive prefix for this thread's 4 elems
  for (int j = 0; j < 4; ++j) {
    int i = idx + j;
    if (i < N) {
      off[i] = ex;
      cur[i] = ex;
      isd[i] = rsqrtf((float)(c[j] + 1));  // +1 self-loop
      ex += c[j];
    }
  }
}

__global__ void fill_k(const int* __restrict__ src, const int* __restrict__ dst,
                       int* __restrict__ cur, int* __restrict__ csr, int E) {
  int e = blockIdx.x * blockDim.x + threadIdx.x;
  if (e < E) {
    int d = dst[e];
    int pos = atomicAdd(&cur[d], 1);
    csr[pos] = src[e];
  }
}

// ---------- weight convert: W[k][n] f32 -> Wt[n][k] bf16 ----------
__global__ void wconv_k(const float* __restrict__ W0, const float* __restrict__ W1,
                        const float* __restrict__ W2, unsigned short* __restrict__ Wt) {
  int idx = blockIdx.x * blockDim.x + threadIdx.x;  // 0 .. 3*65536
  int w = idx >> 16; int r = idx & 65535;
  int k = r >> 8, n = r & 255;
  const float* W = (w == 0) ? W0 : (w == 1) ? W1 : W2;
  Wt[(size_t)w * 65536 + n * 256 + k] = f2bf(W[k * 256 + n]);
}

// ---------- GEMM: P[i][:] = bf16((X[i][:] @ W) * isd[i]) ----------
template <bool F32IN>
__global__ __launch_bounds__(256) void gemm_k(const void* __restrict__ Xv,
                                              const unsigned short* __restrict__ Wt,
                                              unsigned short* __restrict__ P,
                                              const float* __restrict__ isd, int M) {
  __shared__ __align__(16) short As[BM * LDR];       // 5120 B
  __shared__ __align__(16) short Bs[D_FEAT * LDR];   // 20480 B
  int t = threadIdx.x;
  int lane = t & 63;
  int wave = t >> 6;              // 0..3 -> 64-col quadrant
  int row0 = blockIdx.x * BM;
  int l15 = lane & 15;
  int l4  = lane >> 4;

  f32x4 acc[4][4];
  for (int m = 0; m < 4; ++m)
    for (int n = 0; n < 4; ++n)
      acc[m][n] = (f32x4){0.f, 0.f, 0.f, 0.f};

  for (int k0 = 0; k0 < D_FEAT; k0 += BK) {
    if constexpr (F32IN) {
      const float* X = (const float*)Xv;
      // stage A: 64 rows x 32 k, f32 -> bf16
      for (int i = 0; i < 2; ++i) {
        int g = t + i * 256;            // 0..511
        int r = g >> 3, c4 = g & 7;
        int grow = row0 + r;
        f32x4 v = (f32x4){0.f, 0.f, 0.f, 0.f};
        if (grow < M) v = *(const f32x4*)(X + (size_t)grow * D_FEAT + k0 + c4 * 4);
        s16x4 b;
        b.x = (short)f2bf(v.x); b.y = (short)f2bf(v.y);
        b.z = (short)f2bf(v.z); b.w = (short)f2bf(v.w);
        *(s16x4*)&As[r * LDR + c4 * 4] = b;
      }
    } else {
      const unsigned short* X = (const unsigned short*)Xv;
      int r = t >> 2, c = t & 3;        // 64 rows x 4 chunks of 8 bf16
      int grow = row0 + r;
      s16x8 v = {0, 0, 0, 0, 0, 0, 0, 0};
      if (grow < M) v = *(const s16x8*)(X + (size_t)grow * D_FEAT + k0 + c * 8);
      *(s16x8*)&As[r * LDR + c * 8] = v;
    }
    // stage B: Wt rows (already [n][k] bf16), 256 rows x 32 k
    for (int i = 0; i < 4; ++i) {
      int g = t + i * 256;            // 0..1023
      int n = g >> 2, c = g & 3;
      i32x4 v = *(const i32x4*)(Wt + (size_t)n * D_FEAT + k0 + c * 8);
      *(i32x4*)&Bs[n * LDR + c * 8] = v;
    }
    __syncthreads();
    s16x8 a[4], b[4];
    for (int m = 0; m < 4; ++m)
      a[m] = *(const s16x8*)&As[(m * 16 + l15) * LDR + l4 * 8];
    for (int n = 0; n < 4; ++n)
      b[n] = *(const s16x8*)&Bs[(wave * 64 + n * 16 + l15) * LDR + l4 * 8];
    for (int m = 0; m < 4; ++m)
      for (int n = 0; n < 4; ++n)
        acc[m][n] = __builtin_amdgcn_mfma_f32_16x16x32_bf16(a[m], b[n], acc[m][n], 0, 0, 0);
    __syncthreads();
  }

  // epilogue: C/D layout col=lane&15, row=4*(lane>>4)+reg
  for (int m = 0; m < 4; ++m) {
    int rbase = row0 + m * 16 + l4 * 4;
    for (int r = 0; r < 4; ++r) {
      int row = rbase + r;
      if (row >= M) continue;
      float sc = isd[row];
      for (int n = 0; n < 4; ++n) {
        int col = wave * 64 + n * 16 + l15;
        P[(size_t)row * D_FEAT + col] = f2bf(acc[m][n][r] * sc);
      }
    }
  }
}

// ---------- aggregation: H[i] = bf16(relu((P[i] + sum_{s in N(i)} P[s]) * isd[i] + b)) ----------
__global__ __launch_bounds__(256) void agg_k(const unsigned short* __restrict__ P,
                                             const int* __restrict__ csr,
                                             const int* __restrict__ off,
                                             const float* __restrict__ isd,
                                             const float* __restrict__ bias,
                                             unsigned short* __restrict__ H, int N) {
  int gid = blockIdx.x * blockDim.x + threadIdx.x;
  int node = gid >> 6;
  int lane = gid & 63;
  if (node >= N) return;
  const s16x4* P4 = (const s16x4*)P;   // 4 bf16 = 8 B per lane
  f32x4 acc = bf4_to_f32(P4[(size_t)node * 64 + lane]);  // self-loop
  int lo = off[node], hi = off[node + 1];
  int e = lo;
  for (; e + 3 < hi; e += 4) {
    int s0 = csr[e], s1 = csr[e + 1], s2 = csr[e + 2], s3 = csr[e + 3];
    s16x4 v0 = P4[(size_t)s0 * 64 + lane];
    s16x4 v1 = P4[(size_t)s1 * 64 + lane];
    s16x4 v2 = P4[(size_t)s2 * 64 + lane];
    s16x4 v3 = P4[(size_t)s3 * 64 + lane];
    acc += bf4_to_f32(v0);
    acc += bf4_to_f32(v1);
    acc += bf4_to_f32(v2);
    acc += bf4_to_f32(v3);
  }
  for (; e < hi; ++e) {
    acc += bf4_to_f32(P4[(size_t)csr[e] * 64 + lane]);
  }
  float sc = isd[node];
  f32x4 bb = *(const f32x4*)(bias + lane * 4);
  s16x4 o;
  o.x = (short)f2bf(fmaxf(acc.x * sc + bb.x, 0.f));
  o.y = (short)f2bf(fmaxf(acc.y * sc + bb.y, 0.f));
  o.z = (short)f2bf(fmaxf(acc.z * sc + bb.z, 0.f));
  o.w = (short)f2bf(fmaxf(acc.w * sc + bb.w, 0.f));
  ((s16x4*)H)[(size_t)node * 64 + lane] = o;
}

// ---------- pooling ----------
__device__ __forceinline__ int lower_bound_batch(const int* __restrict__ b, int N, int v) {
  int lo = 0, hi = N;
  while (lo < hi) { int mid = (lo + hi) >> 1; if (b[mid] < v) lo = mid + 1; else hi = mid; }
  return lo;
}

__global__ __launch_bounds__(256) void pool_k(const unsigned short* __restrict__ H,
                                              const int* __restrict__ batch,
                                              float* __restrict__ pp, int N) {
  int g = blockIdx.x >> 3;
  int s = blockIdx.x & (NSPLIT - 1);
  int c = threadIdx.x;
  int lo = lower_bound_batch(batch, N, g);
  int hi = lower_bound_batch(batch, N, g + 1);
  int len = hi - lo;
  int slo = lo + (int)(((long long)len * s) >> 3);
  int shi = lo + (int)(((long long)len * (s + 1)) >> 3);
  float sum = 0.f;
  for (int i = slo; i < shi; ++i) sum += bf2f(H[(size_t)i * D_FEAT + c]);
  pp[(g * NSPLIT + s) * D_FEAT + c] = sum;
}

// ---------- FC head ----------
__global__ __launch_bounds__(256) void fc_k(const float* __restrict__ pp,
                                            const int* __restrict__ batch,
                                            const float* __restrict__ fc1w, const float* __restrict__ fc1b,
                                            const float* __restrict__ fc2w, const float* __restrict__ fc2b,
                                            float* __restrict__ out, int N) {
  __shared__ float pl[D_FEAT];
  __shared__ float h1[D_FEAT];
  int g = blockIdx.x, j = threadIdx.x;
  int lo = lower_bound_batch(batch, N, g);
  int hi = lower_bound_batch(batch, N, g + 1);
  float cnt = fmaxf((float)(hi - lo), 1.f);
  float sum = 0.f;
  for (int s = 0; s < NSPLIT; ++s) sum += pp[(g * NSPLIT + s) * D_FEAT + j];
  pl[j] = sum / cnt;
  __syncthreads();
  float a = fc1b[j];
  for (int k = 0; k < D_FEAT; ++k) a += pl[k] * fc1w[k * D_FEAT + j];
  h1[j] = fmaxf(a, 0.f);
  __syncthreads();
  if (j < 128) {
    float o = fc2b[j];
    for (int k = 0; k < D_FEAT; ++k) o += h1[k] * fc2w[k * 128 + j];
    out[g * 128 + j] = o;
  }
}

extern "C" void kernel_launch(void* const* d_in, const int* in_sizes, int n_in,
                              void* d_out, int out_size, void* d_ws, size_t ws_size,
                              hipStream_t stream) {
  const float* x    = (const float*)d_in[0];
  const int*   ei   = (const int*)d_in[1];
  const int*   batch= (const int*)d_in[2];
  const float* W0   = (const float*)d_in[3];
  const float* b0   = (const float*)d_in[4];
  const float* W1   = (const float*)d_in[5];
  const float* b1   = (const float*)d_in[6];
  const float* W2   = (const float*)d_in[7];
  const float* b2   = (const float*)d_in[8];
  const float* fc1w = (const float*)d_in[9];
  const float* fc1b = (const float*)d_in[10];
  const float* fc2w = (const float*)d_in[11];
  const float* fc2b = (const float*)d_in[12];
  float* out = (float*)d_out;

  int N = in_sizes[0] / D_FEAT;   // 50000
  int E = in_sizes[1] / 2;        // 800000
  const int* srcE = ei;
  const int* dstE = ei + E;
  int nb = (N + SCAN_CHUNK - 1) / SCAN_CHUNK;  // 49

  // workspace carve
  char* w = (char*)d_ws;
  auto alloc = [&](size_t bytes) { char* p = w; w += (bytes + 255) & ~(size_t)255; return p; };
  int*   counts = (int*)  alloc((size_t)N * 4);
  int*   off    = (int*)  alloc((size_t)(N + 1) * 4);
  int*   cur    = (int*)  alloc((size_t)N * 4);
  float* isd    = (float*)alloc((size_t)N * 4);
  int*   csr    = (int*)  alloc((size_t)E * 4);
  int*   bsum   = (int*)  alloc((size_t)nb * 4);
  int*   boff   = (int*)  alloc((size_t)nb * 4);
  unsigned short* Wt = (unsigned short*)alloc((size_t)3 * 65536 * 2);
  unsigned short* P = (unsigned short*)alloc((size_t)N * D_FEAT * 2);
  unsigned short* H = (unsigned short*)alloc((size_t)N * D_FEAT * 2);
  float* pp     = (float*)alloc((size_t)NGRAPH * NSPLIT * D_FEAT * 4);

  hipMemsetAsync(counts, 0, (size_t)N * 4, stream);
  hist_k<<<(E + 255) / 256, 256, 0, stream>>>(dstE, counts, E);
  bsum_k<<<nb, 256, 0, stream>>>(counts, bsum, N);
  bscan_k<<<1, 1024, 0, stream>>>(bsum, boff, off + N, nb);
  fillscan_k<<<nb, 256, 0, stream>>>(counts, boff, off, cur, isd, N);
  fill_k<<<(E + 255) / 256, 256, 0, stream>>>(srcE, dstE, cur, csr, E);
  wconv_k<<<768, 256, 0, stream>>>(W0, W1, W2, Wt);

  int gblocks = (N + BM - 1) / BM;
  int ablocks = (N * 64 + 255) / 256;

  gemm_k<true> <<<gblocks, 256, 0, stream>>>(x, Wt,             P, isd, N);
  agg_k        <<<ablocks, 256, 0, stream>>>(P, csr, off, isd, b0, H, N);
  gemm_k<false><<<gblocks, 256, 0, stream>>>(H, Wt + 65536,     P, isd, N);
  agg_k        <<<ablocks, 256, 0, stream>>>(P, csr, off, isd, b1, H, N);
  gemm_k<false><<<gblocks, 256, 0, stream>>>(H, Wt + 2 * 65536, P, isd, N);
  agg_k        <<<ablocks, 256, 0, stream>>>(P, csr, off, isd, b2, H, N);

  pool_k<<<NGRAPH * NSPLIT, 256, 0, stream>>>(H, batch, pp, N);
  fc_k  <<<NGRAPH, 256, 0, stream>>>(pp, batch, fc1w, fc1b, fc2w, fc2b, out, N);
}

// Round 4
// 408.271 us; speedup vs baseline: 1.8102x; 1.0020x over previous
//
#include <hip/hip_runtime.h>
#include <stdint.h>

#define D_FEAT 256
#define NGRAPH 64
#define NSPLIT 8
#define BM 64
#define BK 32
#define LDR 40   // LDS row stride in bf16 elems (80B: 16B-aligned, 2-way-max bank pattern)
#define SCAN_CHUNK 1024

using f32x4 = __attribute__((ext_vector_type(4))) float;
using s16x8 = __attribute__((ext_vector_type(8))) short;
using s16x4 = __attribute__((ext_vector_type(4))) short;
using i32x4 = __attribute__((ext_vector_type(4))) int;

__device__ __forceinline__ unsigned short f2bf(float f) {
  union { float f; unsigned u; } v; v.f = f;
  return (unsigned short)((v.u + 0x7FFFu + ((v.u >> 16) & 1u)) >> 16);  // RNE
}
__device__ __forceinline__ float bf2f(unsigned short h) {
  union { unsigned u; float f; } v; v.u = ((unsigned)h) << 16; return v.f;
}

// ---------- CSR build ----------
__global__ void hist_k(const int* __restrict__ dst, int* __restrict__ counts, int E) {
  int e = blockIdx.x * blockDim.x + threadIdx.x;
  if (e < E) atomicAdd(&counts[dst[e]], 1);
}

// Phase A: per-block (1024-elem chunk) sums of PADDED counts (pad odd->even)
__global__ __launch_bounds__(256) void bsum_k(const int* __restrict__ counts,
                                              int* __restrict__ bsum, int N) {
  int base = blockIdx.x * SCAN_CHUNK;
  int t = threadIdx.x;
  int idx = base + t * 4;
  int s = 0;
  for (int j = 0; j < 4; ++j) {
    if (idx + j < N) { int c = counts[idx + j]; s += c + (c & 1); }
  }
  for (int d = 1; d < 64; d <<= 1) s += __shfl_xor(s, d);
  __shared__ int ws[4];
  if ((t & 63) == 0) ws[t >> 6] = s;
  __syncthreads();
  if (t == 0) bsum[blockIdx.x] = ws[0] + ws[1] + ws[2] + ws[3];
}

// Phase B: scan the block sums (nb <= 1024), write total to offN
__global__ __launch_bounds__(1024) void bscan_k(const int* __restrict__ bsum,
                                                int* __restrict__ boff,
                                                int* __restrict__ offN, int nb) {
  __shared__ int part[1024];
  int t = threadIdx.x;
  int v = (t < nb) ? bsum[t] : 0;
  part[t] = v;
  __syncthreads();
  for (int d = 1; d < 1024; d <<= 1) {
    int u = (t >= d) ? part[t - d] : 0;
    __syncthreads();
    part[t] += u;
    __syncthreads();
  }
  if (t < nb) boff[t] = part[t] - v;
  if (t == 1023) offN[0] = part[1023];
}

// Phase C: in-block scan (padded counts) + block offset -> off/cur/isd
__global__ __launch_bounds__(256) void fillscan_k(const int* __restrict__ counts,
                                                  const int* __restrict__ boff,
                                                  int* __restrict__ off, int* __restrict__ cur,
                                                  float* __restrict__ isd, int N) {
  int b = blockIdx.x;
  int base = b * SCAN_CHUNK;
  int t = threadIdx.x;
  int idx = base + t * 4;
  int c[4], cp[4];
  int s = 0;
  for (int j = 0; j < 4; ++j) {
    c[j] = (idx + j < N) ? counts[idx + j] : 0;
    cp[j] = c[j] + (c[j] & 1);   // pad to even
    s += cp[j];
  }
  int inc = s;
  int lane = t & 63;
  for (int d = 1; d < 64; d <<= 1) {
    int u = __shfl_up(inc, d);
    if (lane >= d) inc += u;
  }
  __shared__ int wtot[4];
  if (lane == 63) wtot[t >> 6] = inc;
  __syncthreads();
  int woff = 0;
  for (int w = 0; w < (t >> 6); ++w) woff += wtot[w];
  int ex = boff[b] + woff + inc - s;  // exclusive prefix (padded) for this thread's 4 elems
  for (int j = 0; j < 4; ++j) {
    int i = idx + j;
    if (i < N) {
      off[i] = ex;
      cur[i] = ex;
      isd[i] = rsqrtf((float)(c[j] + 1));  // real degree +1 self-loop
      ex += cp[j];
    }
  }
}

// init csr with sentinel N; zero sentinel rows P[N][:], H[N][:]
__global__ __launch_bounds__(256) void csrinit_k(int* __restrict__ csr, int cap4,
                                                 unsigned int* __restrict__ Prow,
                                                 unsigned int* __restrict__ Hrow, int N) {
  int t = blockIdx.x * blockDim.x + threadIdx.x;
  if (t < cap4) {
    i32x4 v = (i32x4){N, N, N, N};
    ((i32x4*)csr)[t] = v;
  }
  if (blockIdx.x == 0) {
    int j = threadIdx.x;
    if (j < 128) Prow[j] = 0u;
    else Hrow[j - 128] = 0u;
  }
}

__global__ void fill_k(const int* __restrict__ src, const int* __restrict__ dst,
                       int* __restrict__ cur, int* __restrict__ csr, int E) {
  int e = blockIdx.x * blockDim.x + threadIdx.x;
  if (e < E) {
    int d = dst[e];
    int pos = atomicAdd(&cur[d], 1);
    csr[pos] = src[e];
  }
}

// ---------- weight convert: W[k][n] f32 -> Wt[n][k] bf16 ----------
__global__ void wconv_k(const float* __restrict__ W0, const float* __restrict__ W1,
                        const float* __restrict__ W2, unsigned short* __restrict__ Wt) {
  int idx = blockIdx.x * blockDim.x + threadIdx.x;  // 0 .. 3*65536
  int w = idx >> 16; int r = idx & 65535;
  int k = r >> 8, n = r & 255;
  const float* W = (w == 0) ? W0 : (w == 1) ? W1 : W2;
  Wt[(size_t)w * 65536 + n * 256 + k] = f2bf(W[k * 256 + n]);
}

// ---------- GEMM: P[i][:] = bf16((X[i][:] @ W) * isd[i]) ----------
template <bool F32IN>
__global__ __launch_bounds__(256) void gemm_k(const void* __restrict__ Xv,
                                              const unsigned short* __restrict__ Wt,
                                              unsigned short* __restrict__ P,
                                              const float* __restrict__ isd, int M) {
  __shared__ __align__(16) short As[BM * LDR];       // 5120 B
  __shared__ __align__(16) short Bs[D_FEAT * LDR];   // 20480 B
  int t = threadIdx.x;
  int lane = t & 63;
  int wave = t >> 6;              // 0..3 -> 64-col quadrant
  int row0 = blockIdx.x * BM;
  int l15 = lane & 15;
  int l4  = lane >> 4;

  f32x4 acc[4][4];
  for (int m = 0; m < 4; ++m)
    for (int n = 0; n < 4; ++n)
      acc[m][n] = (f32x4){0.f, 0.f, 0.f, 0.f};

  for (int k0 = 0; k0 < D_FEAT; k0 += BK) {
    if constexpr (F32IN) {
      const float* X = (const float*)Xv;
      // stage A: 64 rows x 32 k, f32 -> bf16
      for (int i = 0; i < 2; ++i) {
        int g = t + i * 256;            // 0..511
        int r = g >> 3, c4 = g & 7;
        int grow = row0 + r;
        f32x4 v = (f32x4){0.f, 0.f, 0.f, 0.f};
        if (grow < M) v = *(const f32x4*)(X + (size_t)grow * D_FEAT + k0 + c4 * 4);
        s16x4 b;
        b.x = (short)f2bf(v.x); b.y = (short)f2bf(v.y);
        b.z = (short)f2bf(v.z); b.w = (short)f2bf(v.w);
        *(s16x4*)&As[r * LDR + c4 * 4] = b;
      }
    } else {
      const unsigned short* X = (const unsigned short*)Xv;
      int r = t >> 2, c = t & 3;        // 64 rows x 4 chunks of 8 bf16
      int grow = row0 + r;
      s16x8 v = {0, 0, 0, 0, 0, 0, 0, 0};
      if (grow < M) v = *(const s16x8*)(X + (size_t)grow * D_FEAT + k0 + c * 8);
      *(s16x8*)&As[r * LDR + c * 8] = v;
    }
    // stage B: Wt rows (already [n][k] bf16), 256 rows x 32 k
    for (int i = 0; i < 4; ++i) {
      int g = t + i * 256;            // 0..1023
      int n = g >> 2, c = g & 3;
      i32x4 v = *(const i32x4*)(Wt + (size_t)n * D_FEAT + k0 + c * 8);
      *(i32x4*)&Bs[n * LDR + c * 8] = v;
    }
    __syncthreads();
    s16x8 a[4], b[4];
    for (int m = 0; m < 4; ++m)
      a[m] = *(const s16x8*)&As[(m * 16 + l15) * LDR + l4 * 8];
    for (int n = 0; n < 4; ++n)
      b[n] = *(const s16x8*)&Bs[(wave * 64 + n * 16 + l15) * LDR + l4 * 8];
    for (int m = 0; m < 4; ++m)
      for (int n = 0; n < 4; ++n)
        acc[m][n] = __builtin_amdgcn_mfma_f32_16x16x32_bf16(a[m], b[n], acc[m][n], 0, 0, 0);
    __syncthreads();
  }

  // epilogue: C/D layout col=lane&15, row=4*(lane>>4)+reg
  for (int m = 0; m < 4; ++m) {
    int rbase = row0 + m * 16 + l4 * 4;
    for (int r = 0; r < 4; ++r) {
      int row = rbase + r;
      if (row >= M) continue;
      float sc = isd[row];
      for (int n = 0; n < 4; ++n) {
        int col = wave * 64 + n * 16 + l15;
        P[(size_t)row * D_FEAT + col] = f2bf(acc[m][n][r] * sc);
      }
    }
  }
}

// ---------- aggregation: H[i] = bf16(relu((P[i] + sum_{s in N(i)} P[s]) * isd[i] + b))
// paired-edge gather: lanes 0-31 take edge e, lanes 32-63 take edge e+1 (16 B/lane).
// CSR lists are even-length (sentinel row N is all zeros in P).
__global__ __launch_bounds__(256) void agg_k(const unsigned short* __restrict__ P,
                                             const int* __restrict__ csr,
                                             const int* __restrict__ off,
                                             const float* __restrict__ isd,
                                             const float* __restrict__ bias,
                                             unsigned short* __restrict__ H, int N) {
  int gid = blockIdx.x * blockDim.x + threadIdx.x;
  int node = gid >> 6;
  if (node >= N) return;
  int lane = gid & 63;
  int half = lane >> 5;   // 0 or 1
  int col  = lane & 31;   // 16B chunk within row
  const s16x8* P8 = (const s16x8*)P;   // 32 chunks per row

  float acc[8];
  {
    // self term once (half 0 real row, half 1 sentinel zero row)
    int si = half ? N : node;
    s16x8 v = P8[(size_t)si * 32 + col];
    for (int j = 0; j < 8; ++j) acc[j] = bf2f((unsigned short)v[j]);
  }

  int lo = off[node], hi = off[node + 1];
  int e = lo;
  for (; e + 8 <= hi; e += 8) {
    int i0 = csr[e + 0 + half];
    int i1 = csr[e + 2 + half];
    int i2 = csr[e + 4 + half];
    int i3 = csr[e + 6 + half];
    s16x8 v0 = P8[(size_t)i0 * 32 + col];
    s16x8 v1 = P8[(size_t)i1 * 32 + col];
    s16x8 v2 = P8[(size_t)i2 * 32 + col];
    s16x8 v3 = P8[(size_t)i3 * 32 + col];
    for (int j = 0; j < 8; ++j) acc[j] += bf2f((unsigned short)v0[j]);
    for (int j = 0; j < 8; ++j) acc[j] += bf2f((unsigned short)v1[j]);
    for (int j = 0; j < 8; ++j) acc[j] += bf2f((unsigned short)v2[j]);
    for (int j = 0; j < 8; ++j) acc[j] += bf2f((unsigned short)v3[j]);
  }
  for (; e < hi; e += 2) {
    int i = csr[e + half];
    s16x8 v = P8[(size_t)i * 32 + col];
    for (int j = 0; j < 8; ++j) acc[j] += bf2f((unsigned short)v[j]);
  }

  // fold the two halves (lanes l and l+32 hold the same 8 columns)
  for (int j = 0; j < 8; ++j) acc[j] += __shfl_xor(acc[j], 32);

  if (half == 0) {
    float sc = isd[node];
    f32x4 b0 = *(const f32x4*)(bias + col * 8);
    f32x4 b1 = *(const f32x4*)(bias + col * 8 + 4);
    s16x8 o;
    o[0] = (short)f2bf(fmaxf(acc[0] * sc + b0.x, 0.f));
    o[1] = (short)f2bf(fmaxf(acc[1] * sc + b0.y, 0.f));
    o[2] = (short)f2bf(fmaxf(acc[2] * sc + b0.z, 0.f));
    o[3] = (short)f2bf(fmaxf(acc[3] * sc + b0.w, 0.f));
    o[4] = (short)f2bf(fmaxf(acc[4] * sc + b1.x, 0.f));
    o[5] = (short)f2bf(fmaxf(acc[5] * sc + b1.y, 0.f));
    o[6] = (short)f2bf(fmaxf(acc[6] * sc + b1.z, 0.f));
    o[7] = (short)f2bf(fmaxf(acc[7] * sc + b1.w, 0.f));
    ((s16x8*)H)[(size_t)node * 32 + col] = o;
  }
}

// ---------- pooling ----------
__device__ __forceinline__ int lower_bound_batch(const int* __restrict__ b, int N, int v) {
  int lo = 0, hi = N;
  while (lo < hi) { int mid = (lo + hi) >> 1; if (b[mid] < v) lo = mid + 1; else hi = mid; }
  return lo;
}

__global__ __launch_bounds__(256) void pool_k(const unsigned short* __restrict__ H,
                                              const int* __restrict__ batch,
                                              float* __restrict__ pp, int N) {
  int g = blockIdx.x >> 3;
  int s = blockIdx.x & (NSPLIT - 1);
  int c = threadIdx.x;
  int lo = lower_bound_batch(batch, N, g);
  int hi = lower_bound_batch(batch, N, g + 1);
  int len = hi - lo;
  int slo = lo + (int)(((long long)len * s) >> 3);
  int shi = lo + (int)(((long long)len * (s + 1)) >> 3);
  float sum = 0.f;
  for (int i = slo; i < shi; ++i) sum += bf2f(H[(size_t)i * D_FEAT + c]);
  pp[(g * NSPLIT + s) * D_FEAT + c] = sum;
}

// ---------- FC head ----------
__global__ __launch_bounds__(256) void fc_k(const float* __restrict__ pp,
                                            const int* __restrict__ batch,
                                            const float* __restrict__ fc1w, const float* __restrict__ fc1b,
                                            const float* __restrict__ fc2w, const float* __restrict__ fc2b,
                                            float* __restrict__ out, int N) {
  __shared__ float pl[D_FEAT];
  __shared__ float h1[D_FEAT];
  int g = blockIdx.x, j = threadIdx.x;
  int lo = lower_bound_batch(batch, N, g);
  int hi = lower_bound_batch(batch, N, g + 1);
  float cnt = fmaxf((float)(hi - lo), 1.f);
  float sum = 0.f;
  for (int s = 0; s < NSPLIT; ++s) sum += pp[(g * NSPLIT + s) * D_FEAT + j];
  pl[j] = sum / cnt;
  __syncthreads();
  float a = fc1b[j];
  for (int k = 0; k < D_FEAT; ++k) a += pl[k] * fc1w[k * D_FEAT + j];
  h1[j] = fmaxf(a, 0.f);
  __syncthreads();
  if (j < 128) {
    float o = fc2b[j];
    for (int k = 0; k < D_FEAT; ++k) o += h1[k] * fc2w[k * 128 + j];
    out[g * 128 + j] = o;
  }
}

extern "C" void kernel_launch(void* const* d_in, const int* in_sizes, int n_in,
                              void* d_out, int out_size, void* d_ws, size_t ws_size,
                              hipStream_t stream) {
  const float* x    = (const float*)d_in[0];
  const int*   ei   = (const int*)d_in[1];
  const int*   batch= (const int*)d_in[2];
  const float* W0   = (const float*)d_in[3];
  const float* b0   = (const float*)d_in[4];
  const float* W1   = (const float*)d_in[5];
  const float* b1   = (const float*)d_in[6];
  const float* W2   = (const float*)d_in[7];
  const float* b2   = (const float*)d_in[8];
  const float* fc1w = (const float*)d_in[9];
  const float* fc1b = (const float*)d_in[10];
  const float* fc2w = (const float*)d_in[11];
  const float* fc2b = (const float*)d_in[12];
  float* out = (float*)d_out;

  int N = in_sizes[0] / D_FEAT;   // 50000
  int E = in_sizes[1] / 2;        // 800000
  const int* srcE = ei;
  const int* dstE = ei + E;
  int nb = (N + SCAN_CHUNK - 1) / SCAN_CHUNK;  // 49
  int Ecap = E + N;               // padded-CSR upper bound

  // workspace carve
  char* w = (char*)d_ws;
  auto alloc = [&](size_t bytes) { char* p = w; w += (bytes + 255) & ~(size_t)255; return p; };
  int*   counts = (int*)  alloc((size_t)N * 4);
  int*   off    = (int*)  alloc((size_t)(N + 1) * 4);
  int*   cur    = (int*)  alloc((size_t)N * 4);
  float* isd    = (float*)alloc((size_t)N * 4);
  int*   csr    = (int*)  alloc((size_t)(Ecap + 4) * 4);
  int*   bsum   = (int*)  alloc((size_t)nb * 4);
  int*   boff   = (int*)  alloc((size_t)nb * 4);
  unsigned short* Wt = (unsigned short*)alloc((size_t)3 * 65536 * 2);
  unsigned short* P = (unsigned short*)alloc((size_t)(N + 1) * D_FEAT * 2);  // +1 sentinel row
  unsigned short* H = (unsigned short*)alloc((size_t)(N + 1) * D_FEAT * 2);
  float* pp     = (float*)alloc((size_t)NGRAPH * NSPLIT * D_FEAT * 4);

  hipMemsetAsync(counts, 0, (size_t)N * 4, stream);
  hist_k<<<(E + 255) / 256, 256, 0, stream>>>(dstE, counts, E);
  bsum_k<<<nb, 256, 0, stream>>>(counts, bsum, N);
  bscan_k<<<1, 1024, 0, stream>>>(bsum, boff, off + N, nb);
  fillscan_k<<<nb, 256, 0, stream>>>(counts, boff, off, cur, isd, N);
  int cap4 = (Ecap + 3) / 4;
  csrinit_k<<<(cap4 + 255) / 256, 256, 0, stream>>>(csr, cap4,
      (unsigned int*)(P + (size_t)N * D_FEAT), (unsigned int*)(H + (size_t)N * D_FEAT), N);
  fill_k<<<(E + 255) / 256, 256, 0, stream>>>(srcE, dstE, cur, csr, E);
  wconv_k<<<768, 256, 0, stream>>>(W0, W1, W2, Wt);

  int gblocks = (N + BM - 1) / BM;
  int ablocks = (N * 64 + 255) / 256;

  gemm_k<true> <<<gblocks, 256, 0, stream>>>(x, Wt,             P, isd, N);
  agg_k        <<<ablocks, 256, 0, stream>>>(P, csr, off, isd, b0, H, N);
  gemm_k<false><<<gblocks, 256, 0, stream>>>(H, Wt + 65536,     P, isd, N);
  agg_k        <<<ablocks, 256, 0, stream>>>(P, csr, off, isd, b1, H, N);
  gemm_k<false><<<gblocks, 256, 0, stream>>>(H, Wt + 2 * 65536, P, isd, N);
  agg_k        <<<ablocks, 256, 0, stream>>>(P, csr, off, isd, b2, H, N);

  pool_k<<<NGRAPH * NSPLIT, 256, 0, stream>>>(H, batch, pp, N);
  fc_k  <<<NGRAPH, 256, 0, stream>>>(pp, batch, fc1w, fc1b, fc2w, fc2b, out, N);
}